// Round 2
// baseline (408.131 us; speedup 1.0000x reference)
//
#include <hip/hip_runtime.h>
#include <math.h>

#define F_IN   128
#define HEADS  4
#define HID    32
#define NCLS   8
#define SLOPE  0.2f

// ---------------------------------------------------------------------------
// Edge-index layout detection (int32 vs int64 storage) — device side only.
// If stored as int64 (values < 2^31, non-negative), every odd 32-bit word of
// the first 2*256 words is zero. With int32 storage those words are random
// node ids; P(256 consecutive zeros) ~ (1/50000)^256 ~ 0.
// flag = 1  -> int32 layout,  flag = 0 -> int64 layout
// ---------------------------------------------------------------------------
__global__ void k_detect(const int* __restrict__ ei, int* __restrict__ flag) {
    __shared__ int nz;
    if (threadIdx.x == 0) nz = 0;
    __syncthreads();
    int v = ei[2 * threadIdx.x + 1];
    if (v != 0) atomicAdd(&nz, 1);
    __syncthreads();
    if (threadIdx.x == 0) *flag = (nz > 0) ? 1 : 0;
}

__global__ void k_convert(const int* __restrict__ ei, const int* __restrict__ flag,
                          int* __restrict__ s32, int* __restrict__ d32, int E) {
    int e = blockIdx.x * 256 + threadIdx.x;
    if (e >= E) return;
    if (*flag) {                 // int32: [src[0..E), dst[0..E)]
        s32[e] = ei[e];
        d32[e] = ei[E + e];
    } else {                     // int64: low words at even indices
        s32[e] = ei[2 * e];
        d32[e] = ei[2 * E + 2 * e];
    }
}

// ---------------------------------------------------------------------------
// CSR build (destination-sorted incoming-edge lists, self-loops included)
// ---------------------------------------------------------------------------
__global__ void k_deg_init(int* __restrict__ deg, int N) {
    int i = blockIdx.x * 256 + threadIdx.x;
    if (i < N) deg[i] = 1;                    // self loop
}

__global__ void k_deg_count(const int* __restrict__ d32, int* __restrict__ deg, int E) {
    int e = blockIdx.x * 256 + threadIdx.x;
    if (e < E) atomicAdd(&deg[d32[e]], 1);
}

// single-block exclusive scan, 1024 threads, wave-shuffle inner scan
__global__ void k_scan(const int* __restrict__ deg, int* __restrict__ offs, int N) {
    __shared__ int wsum[16];
    __shared__ int carry;
    int lane = threadIdx.x & 63;
    int wid  = threadIdx.x >> 6;
    if (threadIdx.x == 0) carry = 0;
    __syncthreads();
    for (int base = 0; base < N; base += 1024) {
        int i = base + threadIdx.x;
        int v = (i < N) ? deg[i] : 0;
        int incl = v;
        #pragma unroll
        for (int off = 1; off < 64; off <<= 1) {
            int t = __shfl_up(incl, off, 64);
            if (lane >= off) incl += t;
        }
        if (lane == 63) wsum[wid] = incl;
        __syncthreads();
        if (threadIdx.x == 0) {
            int run = carry;
            #pragma unroll
            for (int w = 0; w < 16; w++) { int t = wsum[w]; wsum[w] = run; run += t; }
            carry = run;
        }
        __syncthreads();
        if (i < N) offs[i] = wsum[wid] + incl - v;
        __syncthreads();
    }
    if (threadIdx.x == 0) offs[N] = carry;
}

__global__ void k_cursor(const int* __restrict__ offs, int* __restrict__ cur, int N) {
    int i = blockIdx.x * 256 + threadIdx.x;
    if (i < N) cur[i] = offs[i];
}

__global__ void k_fill(const int* __restrict__ s32, const int* __restrict__ d32,
                       int* __restrict__ cur, int* __restrict__ csr, int E, int N) {
    int i = blockIdx.x * 256 + threadIdx.x;
    if (i >= E + N) return;
    int s, d;
    if (i < E) { s = s32[i]; d = d32[i]; }
    else       { s = i - E;  d = i - E; }     // self loop
    int pos = atomicAdd(&cur[d], 1);
    csr[pos] = s;
}

// ---------------------------------------------------------------------------
// GEMM1: xw1[N,128] = x[N,128] @ W1[128,128]
// 16 rows / block of 256; x tile in LDS; each thread: 8 rows x 1 col.
// ---------------------------------------------------------------------------
__global__ void k_gemm1(const float* __restrict__ x, const float* __restrict__ W,
                        float* __restrict__ xw, int N) {
    __shared__ float xs[16][128];
    int r0 = blockIdx.x * 16;
    for (int i = threadIdx.x; i < 16 * 32; i += 256) {   // 512 float4 = whole tile
        int q = i & 31;            // float4 within row
        int r = i >> 5;            // row in tile
        int gr = r0 + r;
        float4 v = make_float4(0.f, 0.f, 0.f, 0.f);
        if (gr < N) v = ((const float4*)(x + (size_t)gr * 128))[q];
        ((float4*)xs)[i] = v;      // linear float4 index over tile (fixed R1)
    }
    __syncthreads();
    int c  = threadIdx.x & 127;
    int rg = threadIdx.x >> 7;     // 0/1 -> rows rg*8 .. rg*8+7
    float acc[8] = {0.f, 0.f, 0.f, 0.f, 0.f, 0.f, 0.f, 0.f};
    #pragma unroll 8
    for (int k4 = 0; k4 < 32; k4++) {
        float w0 = W[(4 * k4 + 0) * 128 + c];
        float w1 = W[(4 * k4 + 1) * 128 + c];
        float w2 = W[(4 * k4 + 2) * 128 + c];
        float w3 = W[(4 * k4 + 3) * 128 + c];
        #pragma unroll
        for (int i = 0; i < 8; i++) {
            float4 xv = *(const float4*)&xs[rg * 8 + i][4 * k4];
            acc[i] += xv.x * w0 + xv.y * w1 + xv.z * w2 + xv.w * w3;
        }
    }
    #pragma unroll
    for (int i = 0; i < 8; i++) {
        int r = r0 + rg * 8 + i;
        if (r < N) xw[(size_t)r * 128 + c] = acc[i];
    }
}

// ---------------------------------------------------------------------------
// a_src1/a_dst1: per (node, head) dot of xw1 chunk with attention vectors
// ---------------------------------------------------------------------------
__global__ void k_att1(const float* __restrict__ xw, const float* __restrict__ as,
                       const float* __restrict__ ad, float* __restrict__ asrc,
                       float* __restrict__ adst, int N) {
    int idx = blockIdx.x * 256 + threadIdx.x;
    if (idx >= N * HEADS) return;
    int n = idx >> 2, hh = idx & 3;
    const float* v  = xw + (size_t)n * 128 + hh * 32;
    const float* sa = as + hh * 32;
    const float* da = ad + hh * 32;
    float s = 0.f, d = 0.f;
    #pragma unroll
    for (int i = 0; i < 32; i++) { float t = v[i]; s += t * sa[i]; d += t * da[i]; }
    asrc[idx] = s;
    adst[idx] = d;
}

// ---------------------------------------------------------------------------
// Layer-1 aggregation: one wave per destination node, online softmax.
// lane -> head h = lane>>4, channel c = lane&15 (handles c and c+16).
// Writes h_out = relu(agg + b1).
// ---------------------------------------------------------------------------
__global__ void k_agg1(const float* __restrict__ xw, const float* __restrict__ asrc,
                       const float* __restrict__ adst, const int* __restrict__ offs,
                       const int* __restrict__ csr, const float* __restrict__ b1,
                       float* __restrict__ hout, int N) {
    int wave = (blockIdx.x * blockDim.x + threadIdx.x) >> 6;
    int lane = threadIdx.x & 63;
    if (wave >= N) return;
    int n = wave;
    int h = lane >> 4;
    int c = lane & 15;
    float adst_h = adst[n * 4 + h];
    int beg = offs[n], end = offs[n + 1];
    float m = -3.0e38f, s = 0.f, acc0 = 0.f, acc1 = 0.f;
    for (int j = beg; j < end; j++) {
        int src = csr[j];
        float e = asrc[src * 4 + h] + adst_h;
        e = (e > 0.f) ? e : SLOPE * e;
        float v0 = xw[(size_t)src * 128 + h * 32 + c];
        float v1 = xw[(size_t)src * 128 + h * 32 + c + 16];
        float mn = fmaxf(m, e);
        float sc = __expf(m - mn);
        float p  = __expf(e - mn);
        s    = s * sc + p;
        acc0 = acc0 * sc + p * v0;
        acc1 = acc1 * sc + p * v1;
        m = mn;
    }
    float inv = 1.f / s;
    float o0 = acc0 * inv + b1[h * 32 + c];
    float o1 = acc1 * inv + b1[h * 32 + c + 16];
    hout[(size_t)n * 128 + h * 32 + c]      = fmaxf(o0, 0.f);
    hout[(size_t)n * 128 + h * 32 + c + 16] = fmaxf(o1, 0.f);
}

// ---------------------------------------------------------------------------
// GEMM2 (+ fused a_src2/a_dst2): xw2[N,8] = h[N,128] @ W2[128,8]
// 32 nodes / block of 256; thread = (node, class); 8-lane shfl reduction
// for the attention dots.
// ---------------------------------------------------------------------------
__global__ void k_gemm2(const float* __restrict__ h, const float* __restrict__ W2,
                        const float* __restrict__ att_s, const float* __restrict__ att_d,
                        float* __restrict__ xw2, float* __restrict__ asrc2,
                        float* __restrict__ adst2, int N) {
    __shared__ float hs[32][132];   // pad 132: bank-conflict-free, 16B aligned
    int r0 = blockIdx.x * 32;
    for (int i = threadIdx.x; i < 32 * 128; i += 256) {
        int r = i >> 7, k = i & 127;
        int gr = r0 + r;
        hs[r][k] = (gr < N) ? h[(size_t)gr * 128 + k] : 0.f;
    }
    __syncthreads();
    int ln = threadIdx.x >> 3, c = threadIdx.x & 7;
    int n = r0 + ln;
    float acc = 0.f;
    #pragma unroll 8
    for (int k4 = 0; k4 < 32; k4++) {
        float4 hv = *(const float4*)&hs[ln][4 * k4];
        acc += hv.x * W2[(4 * k4 + 0) * 8 + c];
        acc += hv.y * W2[(4 * k4 + 1) * 8 + c];
        acc += hv.z * W2[(4 * k4 + 2) * 8 + c];
        acc += hv.w * W2[(4 * k4 + 3) * 8 + c];
    }
    float vs = acc * att_s[c];
    float vd = acc * att_d[c];
    vs += __shfl_xor(vs, 1); vs += __shfl_xor(vs, 2); vs += __shfl_xor(vs, 4);
    vd += __shfl_xor(vd, 1); vd += __shfl_xor(vd, 2); vd += __shfl_xor(vd, 4);
    if (n < N) {
        xw2[n * 8 + c] = acc;
        if (c == 0) { asrc2[n] = vs; adst2[n] = vd; }
    }
}

// ---------------------------------------------------------------------------
// Layer-2 aggregation + log_softmax: 8 lanes per node (8 nodes / wave).
// ---------------------------------------------------------------------------
__global__ void k_agg2(const float* __restrict__ xw2, const float* __restrict__ asrc2,
                       const float* __restrict__ adst2, const int* __restrict__ offs,
                       const int* __restrict__ csr, const float* __restrict__ b2,
                       float* __restrict__ out, int N) {
    int gid  = blockIdx.x * blockDim.x + threadIdx.x;
    int lane = threadIdx.x & 63;
    int node = (gid >> 6) * 8 + (lane >> 3);
    int c    = lane & 7;
    if (node >= N) return;
    float adst = adst2[node];
    int beg = offs[node], end = offs[node + 1];
    float m = -3.0e38f, s = 0.f, acc = 0.f;
    for (int j = beg; j < end; j++) {
        int sidx = csr[j];
        float e = asrc2[sidx] + adst;
        e = (e > 0.f) ? e : SLOPE * e;
        float v = xw2[sidx * 8 + c];
        float mn = fmaxf(m, e);
        float sc = __expf(m - mn);
        float p  = __expf(e - mn);
        s = s * sc + p;
        acc = acc * sc + p * v;
        m = mn;
    }
    float o = acc / s + b2[c];
    // log_softmax across the 8 classes (8 contiguous lanes)
    float mx = o;
    mx = fmaxf(mx, __shfl_xor(mx, 1));
    mx = fmaxf(mx, __shfl_xor(mx, 2));
    mx = fmaxf(mx, __shfl_xor(mx, 4));
    float ex = __expf(o - mx);
    float se = ex;
    se += __shfl_xor(se, 1); se += __shfl_xor(se, 2); se += __shfl_xor(se, 4);
    out[node * 8 + c] = o - mx - __logf(se);
}

// ---------------------------------------------------------------------------
extern "C" void kernel_launch(void* const* d_in, const int* in_sizes, int n_in,
                              void* d_out, int out_size, void* d_ws, size_t ws_size,
                              hipStream_t stream) {
    const float* x   = (const float*)d_in[0];
    const int*   ei  = (const int*)d_in[1];
    const float* W1  = (const float*)d_in[2];
    const float* as1 = (const float*)d_in[3];
    const float* ad1 = (const float*)d_in[4];
    const float* b1  = (const float*)d_in[5];
    const float* W2  = (const float*)d_in[6];
    const float* as2 = (const float*)d_in[7];
    const float* ad2 = (const float*)d_in[8];
    const float* b2  = (const float*)d_in[9];
    float* out = (float*)d_out;

    int N = in_sizes[0] / F_IN;
    int E = in_sizes[1] / 2;
    int ET = E + N;   // edges incl. self loops

    // workspace carve (all regions fully written before read each call)
    char* p = (char*)d_ws;
    auto carve = [&](size_t bytes) { char* q = p; p += (bytes + 255) & ~(size_t)255; return (void*)q; };
    float* xw1   = (float*)carve((size_t)N * 128 * 4);
    float* hbuf  = (float*)carve((size_t)N * 128 * 4);
    float* asrc1 = (float*)carve((size_t)N * 4 * 4);
    float* adst1 = (float*)carve((size_t)N * 4 * 4);
    float* xw2   = (float*)carve((size_t)N * 8 * 4);
    float* asrc2 = (float*)carve((size_t)N * 4);
    float* adst2 = (float*)carve((size_t)N * 4);
    int*   deg   = (int*)carve((size_t)N * 4);
    int*   offs  = (int*)carve((size_t)(N + 1) * 4);
    int*   cur   = (int*)carve((size_t)N * 4);
    int*   s32   = (int*)carve((size_t)E * 4);
    int*   d32   = (int*)carve((size_t)E * 4);
    int*   csr   = (int*)carve((size_t)ET * 4);
    int*   flag  = (int*)carve(256);

    // --- edge layout normalize ---
    k_detect<<<1, 256, 0, stream>>>(ei, flag);
    k_convert<<<(E + 255) / 256, 256, 0, stream>>>(ei, flag, s32, d32, E);

    // --- CSR build ---
    k_deg_init<<<(N + 255) / 256, 256, 0, stream>>>(deg, N);
    k_deg_count<<<(E + 255) / 256, 256, 0, stream>>>(d32, deg, E);
    k_scan<<<1, 1024, 0, stream>>>(deg, offs, N);
    k_cursor<<<(N + 255) / 256, 256, 0, stream>>>(offs, cur, N);
    k_fill<<<(ET + 255) / 256, 256, 0, stream>>>(s32, d32, cur, csr, E, N);

    // --- layer 1 ---
    k_gemm1<<<(N + 15) / 16, 256, 0, stream>>>(x, W1, xw1, N);
    k_att1<<<(N * HEADS + 255) / 256, 256, 0, stream>>>(xw1, as1, ad1, asrc1, adst1, N);
    k_agg1<<<(N + 3) / 4, 256, 0, stream>>>(xw1, asrc1, adst1, offs, csr, b1, hbuf, N);

    // --- layer 2 ---
    k_gemm2<<<(N + 31) / 32, 256, 0, stream>>>(hbuf, W2, as2, ad2, xw2, asrc2, adst2, N);
    k_agg2<<<(N * 8 + 255) / 256, 256, 0, stream>>>(xw2, asrc2, adst2, offs, csr, b2, out, N);
}

// Round 3
// 320.912 us; speedup vs baseline: 1.2718x; 1.2718x over previous
//
#include <hip/hip_runtime.h>
#include <hip/hip_fp16.h>
#include <math.h>

#define F_IN   128
#define HEADS  4
#define HID    32
#define NCLS   8
#define SLOPE  0.2f

// ---------------------------------------------------------------------------
// Edge normalize (int64 vs int32 layout) + deg init, fused.
// Detection: each wave reads the 64 odd words of ei[0..127]; for int64
// storage (values < 2^31) they are all zero; for int32 they are random node
// ids (P(all zero) ~ (1/50000)^64 ~ 0). Wave-uniform ballot, no block sync.
// ---------------------------------------------------------------------------
__global__ void k_convert(const int* __restrict__ ei, int* __restrict__ s32,
                          int* __restrict__ d32, int* __restrict__ deg,
                          int E, int N) {
    int e = blockIdx.x * 256 + threadIdx.x;
    int probe = ei[2 * (threadIdx.x & 63) + 1];
    bool is64 = (__ballot(probe != 0) == 0ULL);
    if (e < N) deg[e] = 1;                    // self loop seed
    if (e >= E) return;
    if (is64) { s32[e] = ei[2 * e]; d32[e] = ei[2 * E + 2 * e]; }
    else      { s32[e] = ei[e];     d32[e] = ei[E + e]; }
}

__global__ void k_deg_count(const int* __restrict__ d32, int* __restrict__ deg, int E) {
    int e = blockIdx.x * 256 + threadIdx.x;
    if (e < E) atomicAdd(&deg[d32[e]], 1);
}

// ---------------------------------------------------------------------------
// Hierarchical exclusive scan: 1024-elem chunks (256 thr x 4), block sums,
// single-wave top scan (supports up to 64 chunks -> N <= 65536), then add.
// ---------------------------------------------------------------------------
__global__ void k_scan1(const int* __restrict__ deg, int* __restrict__ offs,
                        int* __restrict__ bsum, int N) {
    __shared__ int wtot[4];
    __shared__ int wbase[4];
    int tid = threadIdx.x;
    int lane = tid & 63, wid = tid >> 6;
    int i0 = blockIdx.x * 1024 + tid * 4;
    int v[4];
    #pragma unroll
    for (int k = 0; k < 4; k++) v[k] = (i0 + k < N) ? deg[i0 + k] : 0;
    int t = v[0] + v[1] + v[2] + v[3];
    int incl = t;
    #pragma unroll
    for (int off = 1; off < 64; off <<= 1) {
        int u = __shfl_up(incl, off, 64);
        if (lane >= off) incl += u;
    }
    if (lane == 63) wtot[wid] = incl;
    __syncthreads();
    if (tid == 0) {
        int run = 0;
        #pragma unroll
        for (int w = 0; w < 4; w++) { wbase[w] = run; run += wtot[w]; }
        bsum[blockIdx.x] = run;
    }
    __syncthreads();
    int ebase = wbase[wid] + incl - t;
    #pragma unroll
    for (int k = 0; k < 4; k++) {
        if (i0 + k < N) offs[i0 + k] = ebase;
        ebase += v[k];
    }
}

__global__ void k_scan2(int* __restrict__ bsum, int* __restrict__ offs, int NB, int N) {
    int lane = threadIdx.x;           // 64 threads
    int v = (lane < NB) ? bsum[lane] : 0;
    int incl = v;
    #pragma unroll
    for (int off = 1; off < 64; off <<= 1) {
        int u = __shfl_up(incl, off, 64);
        if (lane >= off) incl += u;
    }
    if (lane < NB) bsum[lane] = incl - v;   // exclusive block base
    if (lane == 63) offs[N] = incl;         // grand total
}

__global__ void k_scan3(const int* __restrict__ bsum, int* __restrict__ offs,
                        int* __restrict__ cur, int N) {
    int add = bsum[blockIdx.x];
    int i0 = blockIdx.x * 1024 + threadIdx.x * 4;
    #pragma unroll
    for (int k = 0; k < 4; k++) {
        int i = i0 + k;
        if (i < N) { int o = offs[i] + add; offs[i] = o; cur[i] = o; }
    }
}

__global__ void k_fill(const int* __restrict__ s32, const int* __restrict__ d32,
                       int* __restrict__ cur, int* __restrict__ csr, int E, int N) {
    int i = blockIdx.x * 256 + threadIdx.x;
    if (i >= E + N) return;
    int s, d;
    if (i < E) { s = s32[i]; d = d32[i]; }
    else       { s = i - E;  d = i - E; }     // self loop
    int pos = atomicAdd(&cur[d], 1);
    csr[pos] = s;
}

// ---------------------------------------------------------------------------
// GEMM1: xw1h[N,128] (fp16) = x[N,128] @ W1[128,128], fp32 accumulate.
// 16 rows / block of 256; x tile in LDS; each thread: 8 rows x 1 col.
// ---------------------------------------------------------------------------
__global__ void k_gemm1(const float* __restrict__ x, const float* __restrict__ W,
                        __half* __restrict__ xwh, int N) {
    __shared__ float xs[16][128];
    int r0 = blockIdx.x * 16;
    for (int i = threadIdx.x; i < 16 * 32; i += 256) {   // 512 float4 = whole tile
        int q = i & 31;
        int r = i >> 5;
        int gr = r0 + r;
        float4 v = make_float4(0.f, 0.f, 0.f, 0.f);
        if (gr < N) v = ((const float4*)(x + (size_t)gr * 128))[q];
        ((float4*)xs)[i] = v;
    }
    __syncthreads();
    int c  = threadIdx.x & 127;
    int rg = threadIdx.x >> 7;
    float acc[8] = {0.f, 0.f, 0.f, 0.f, 0.f, 0.f, 0.f, 0.f};
    #pragma unroll 8
    for (int k4 = 0; k4 < 32; k4++) {
        float w0 = W[(4 * k4 + 0) * 128 + c];
        float w1 = W[(4 * k4 + 1) * 128 + c];
        float w2 = W[(4 * k4 + 2) * 128 + c];
        float w3 = W[(4 * k4 + 3) * 128 + c];
        #pragma unroll
        for (int i = 0; i < 8; i++) {
            float4 xv = *(const float4*)&xs[rg * 8 + i][4 * k4];
            acc[i] += xv.x * w0 + xv.y * w1 + xv.z * w2 + xv.w * w3;
        }
    }
    #pragma unroll
    for (int i = 0; i < 8; i++) {
        int r = r0 + rg * 8 + i;
        if (r < N) xwh[(size_t)r * 128 + c] = __float2half(acc[i]);
    }
}

// ---------------------------------------------------------------------------
// a_src1/a_dst1 from fp16 xw (fp32 accumulate)
// ---------------------------------------------------------------------------
__global__ void k_att1(const __half* __restrict__ xwh, const float* __restrict__ as,
                       const float* __restrict__ ad, float* __restrict__ asrc,
                       float* __restrict__ adst, int N) {
    int idx = blockIdx.x * 256 + threadIdx.x;
    if (idx >= N * HEADS) return;
    int n = idx >> 2, hh = idx & 3;
    const __half2* v = (const __half2*)(xwh + (size_t)n * 128 + hh * 32);
    const float* sa = as + hh * 32;
    const float* da = ad + hh * 32;
    float s = 0.f, d = 0.f;
    #pragma unroll
    for (int i = 0; i < 16; i++) {
        float2 t = __half22float2(v[i]);
        s += t.x * sa[2 * i] + t.y * sa[2 * i + 1];
        d += t.x * da[2 * i] + t.y * da[2 * i + 1];
    }
    asrc[idx] = s;
    adst[idx] = d;
}

// ---------------------------------------------------------------------------
// Layer-1 aggregation: one wave per dst node, online softmax, fp16 V gather.
// lane -> head h = lane>>4, channels {ch, ch+1} where ch = h*32 + 2*(lane&15).
// 2-edge unroll keeps two row-gathers in flight per lane.
// ---------------------------------------------------------------------------
__global__ void k_agg1(const __half* __restrict__ xwh, const float* __restrict__ asrc,
                       const float* __restrict__ adst, const int* __restrict__ offs,
                       const int* __restrict__ csr, const float* __restrict__ b1,
                       float* __restrict__ hout, int N) {
    int node = (blockIdx.x * blockDim.x + threadIdx.x) >> 6;
    int lane = threadIdx.x & 63;
    if (node >= N) return;
    int h  = lane >> 4;
    int ch = h * 32 + 2 * (lane & 15);
    float adst_h = adst[node * 4 + h];
    int beg = offs[node], end = offs[node + 1];
    float m = -3.0e38f, s = 0.f, a0 = 0.f, a1 = 0.f;
    int j = beg;
    for (; j + 2 <= end; j += 2) {
        int s0 = csr[j], s1 = csr[j + 1];
        float e0 = asrc[s0 * 4 + h] + adst_h;
        float e1 = asrc[s1 * 4 + h] + adst_h;
        float2 f0 = __half22float2(*(const __half2*)(xwh + (size_t)s0 * 128 + ch));
        float2 f1 = __half22float2(*(const __half2*)(xwh + (size_t)s1 * 128 + ch));
        e0 = (e0 > 0.f) ? e0 : SLOPE * e0;
        e1 = (e1 > 0.f) ? e1 : SLOPE * e1;
        float mn = fmaxf(m, fmaxf(e0, e1));
        float sc = __expf(m - mn);
        float p0 = __expf(e0 - mn);
        float p1 = __expf(e1 - mn);
        s  = s  * sc + p0 + p1;
        a0 = a0 * sc + p0 * f0.x + p1 * f1.x;
        a1 = a1 * sc + p0 * f0.y + p1 * f1.y;
        m = mn;
    }
    if (j < end) {
        int s0 = csr[j];
        float e0 = asrc[s0 * 4 + h] + adst_h;
        float2 f0 = __half22float2(*(const __half2*)(xwh + (size_t)s0 * 128 + ch));
        e0 = (e0 > 0.f) ? e0 : SLOPE * e0;
        float mn = fmaxf(m, e0);
        float sc = __expf(m - mn);
        float p0 = __expf(e0 - mn);
        s  = s  * sc + p0;
        a0 = a0 * sc + p0 * f0.x;
        a1 = a1 * sc + p0 * f0.y;
        m = mn;
    }
    float inv = 1.f / s;
    float o0 = a0 * inv + b1[ch];
    float o1 = a1 * inv + b1[ch + 1];
    hout[(size_t)node * 128 + ch]     = fmaxf(o0, 0.f);
    hout[(size_t)node * 128 + ch + 1] = fmaxf(o1, 0.f);
}

// ---------------------------------------------------------------------------
// GEMM2 (+ fused a_src2/a_dst2): xw2[N,8] = h[N,128] @ W2[128,8]
// ---------------------------------------------------------------------------
__global__ void k_gemm2(const float* __restrict__ h, const float* __restrict__ W2,
                        const float* __restrict__ att_s, const float* __restrict__ att_d,
                        float* __restrict__ xw2, float* __restrict__ asrc2,
                        float* __restrict__ adst2, int N) {
    __shared__ float hs[32][132];   // pad: bank-conflict-free
    int r0 = blockIdx.x * 32;
    for (int i = threadIdx.x; i < 32 * 128; i += 256) {
        int r = i >> 7, k = i & 127;
        int gr = r0 + r;
        hs[r][k] = (gr < N) ? h[(size_t)gr * 128 + k] : 0.f;
    }
    __syncthreads();
    int ln = threadIdx.x >> 3, c = threadIdx.x & 7;
    int n = r0 + ln;
    float acc = 0.f;
    #pragma unroll 8
    for (int k4 = 0; k4 < 32; k4++) {
        float4 hv = *(const float4*)&hs[ln][4 * k4];
        acc += hv.x * W2[(4 * k4 + 0) * 8 + c];
        acc += hv.y * W2[(4 * k4 + 1) * 8 + c];
        acc += hv.z * W2[(4 * k4 + 2) * 8 + c];
        acc += hv.w * W2[(4 * k4 + 3) * 8 + c];
    }
    float vs = acc * att_s[c];
    float vd = acc * att_d[c];
    vs += __shfl_xor(vs, 1); vs += __shfl_xor(vs, 2); vs += __shfl_xor(vs, 4);
    vd += __shfl_xor(vd, 1); vd += __shfl_xor(vd, 2); vd += __shfl_xor(vd, 4);
    if (n < N) {
        xw2[n * 8 + c] = acc;
        if (c == 0) { asrc2[n] = vs; adst2[n] = vd; }
    }
}

// ---------------------------------------------------------------------------
// Layer-2 aggregation + log_softmax: 8 lanes per node, 2-edge unroll.
// ---------------------------------------------------------------------------
__global__ void k_agg2(const float* __restrict__ xw2, const float* __restrict__ asrc2,
                       const float* __restrict__ adst2, const int* __restrict__ offs,
                       const int* __restrict__ csr, const float* __restrict__ b2,
                       float* __restrict__ out, int N) {
    int gid  = blockIdx.x * blockDim.x + threadIdx.x;
    int lane = threadIdx.x & 63;
    int node = (gid >> 6) * 8 + (lane >> 3);
    int c    = lane & 7;
    if (node >= N) return;
    float adst = adst2[node];
    int beg = offs[node], end = offs[node + 1];
    float m = -3.0e38f, s = 0.f, acc = 0.f;
    int j = beg;
    for (; j + 2 <= end; j += 2) {
        int s0 = csr[j], s1 = csr[j + 1];
        float e0 = asrc2[s0] + adst;
        float e1 = asrc2[s1] + adst;
        float v0 = xw2[s0 * 8 + c];
        float v1 = xw2[s1 * 8 + c];
        e0 = (e0 > 0.f) ? e0 : SLOPE * e0;
        e1 = (e1 > 0.f) ? e1 : SLOPE * e1;
        float mn = fmaxf(m, fmaxf(e0, e1));
        float sc = __expf(m - mn);
        float p0 = __expf(e0 - mn);
        float p1 = __expf(e1 - mn);
        s   = s   * sc + p0 + p1;
        acc = acc * sc + p0 * v0 + p1 * v1;
        m = mn;
    }
    if (j < end) {
        int s0 = csr[j];
        float e0 = asrc2[s0] + adst;
        float v0 = xw2[s0 * 8 + c];
        e0 = (e0 > 0.f) ? e0 : SLOPE * e0;
        float mn = fmaxf(m, e0);
        float sc = __expf(m - mn);
        float p0 = __expf(e0 - mn);
        s   = s   * sc + p0;
        acc = acc * sc + p0 * v0;
        m = mn;
    }
    float o = acc / s + b2[c];
    // log_softmax across 8 classes (8 contiguous lanes)
    float mx = o;
    mx = fmaxf(mx, __shfl_xor(mx, 1));
    mx = fmaxf(mx, __shfl_xor(mx, 2));
    mx = fmaxf(mx, __shfl_xor(mx, 4));
    float ex = __expf(o - mx);
    float se = ex;
    se += __shfl_xor(se, 1); se += __shfl_xor(se, 2); se += __shfl_xor(se, 4);
    out[node * 8 + c] = o - mx - __logf(se);
}

// ---------------------------------------------------------------------------
extern "C" void kernel_launch(void* const* d_in, const int* in_sizes, int n_in,
                              void* d_out, int out_size, void* d_ws, size_t ws_size,
                              hipStream_t stream) {
    const float* x   = (const float*)d_in[0];
    const int*   ei  = (const int*)d_in[1];
    const float* W1  = (const float*)d_in[2];
    const float* as1 = (const float*)d_in[3];
    const float* ad1 = (const float*)d_in[4];
    const float* b1  = (const float*)d_in[5];
    const float* W2  = (const float*)d_in[6];
    const float* as2 = (const float*)d_in[7];
    const float* ad2 = (const float*)d_in[8];
    const float* b2  = (const float*)d_in[9];
    float* out = (float*)d_out;

    int N = in_sizes[0] / F_IN;
    int E = in_sizes[1] / 2;
    int ET = E + N;                       // edges incl. self loops
    int NB = (N + 1023) / 1024;           // scan chunks (<=64 for N<=65536)

    // workspace carve (all regions fully written before read each call)
    char* p = (char*)d_ws;
    auto carve = [&](size_t bytes) { char* q = p; p += (bytes + 255) & ~(size_t)255; return (void*)q; };
    __half* xw1h = (__half*)carve((size_t)N * 128 * 2);
    float* hbuf  = (float*)carve((size_t)N * 128 * 4);
    float* asrc1 = (float*)carve((size_t)N * 4 * 4);
    float* adst1 = (float*)carve((size_t)N * 4 * 4);
    float* xw2   = (float*)carve((size_t)N * 8 * 4);
    float* asrc2 = (float*)carve((size_t)N * 4);
    float* adst2 = (float*)carve((size_t)N * 4);
    int*   deg   = (int*)carve((size_t)N * 4);
    int*   offs  = (int*)carve((size_t)(N + 1) * 4);
    int*   cur   = (int*)carve((size_t)N * 4);
    int*   bsum  = (int*)carve(64 * 4);
    int*   s32   = (int*)carve((size_t)E * 4);
    int*   d32   = (int*)carve((size_t)E * 4);
    int*   csr   = (int*)carve((size_t)ET * 4);

    // --- edge normalize + deg init (fused) ---
    k_convert<<<(E + 255) / 256, 256, 0, stream>>>(ei, s32, d32, deg, E, N);
    k_deg_count<<<(E + 255) / 256, 256, 0, stream>>>(d32, deg, E);

    // --- hierarchical scan + cursor ---
    k_scan1<<<NB, 256, 0, stream>>>(deg, offs, bsum, N);
    k_scan2<<<1, 64, 0, stream>>>(bsum, offs, NB, N);
    k_scan3<<<NB, 256, 0, stream>>>(bsum, offs, cur, N);
    k_fill<<<(ET + 255) / 256, 256, 0, stream>>>(s32, d32, cur, csr, E, N);

    // --- layer 1 ---
    k_gemm1<<<(N + 15) / 16, 256, 0, stream>>>(x, W1, xw1h, N);
    k_att1<<<(N * HEADS + 255) / 256, 256, 0, stream>>>(xw1h, as1, ad1, asrc1, adst1, N);
    k_agg1<<<(N + 3) / 4, 256, 0, stream>>>(xw1h, asrc1, adst1, offs, csr, b1, hbuf, N);

    // --- layer 2 ---
    k_gemm2<<<(N + 31) / 32, 256, 0, stream>>>(hbuf, W2, as2, ad2, xw2, asrc2, adst2, N);
    k_agg2<<<(N * 8 + 255) / 256, 256, 0, stream>>>(xw2, asrc2, adst2, offs, csr, b2, out, N);
}

// Round 4
// 304.692 us; speedup vs baseline: 1.3395x; 1.0532x over previous
//
#include <hip/hip_runtime.h>
#include <hip/hip_fp16.h>
#include <math.h>

#define F_IN   128
#define HEADS  4
#define HID    32
#define NCLS   8
#define SLOPE  0.2f

// ---------------------------------------------------------------------------
// deg zero (harness poisons ws each call)
// ---------------------------------------------------------------------------
__global__ void k_zero(int* __restrict__ deg, int N) {
    int i = blockIdx.x * 256 + threadIdx.x;
    if (i < N) deg[i] = 0;
}

// ---------------------------------------------------------------------------
// Edge normalize (int64 vs int32 layout) + degree count, fused.
// Detection: odd words of first 128 ints are all zero iff int64 storage.
// ---------------------------------------------------------------------------
__global__ void k_convert(const int* __restrict__ ei, int* __restrict__ s32,
                          int* __restrict__ d32, int* __restrict__ deg, int E) {
    int e = blockIdx.x * 256 + threadIdx.x;
    int probe = ei[2 * (threadIdx.x & 63) + 1];
    bool is64 = (__ballot(probe != 0) == 0ULL);
    if (e >= E) return;
    int s, d;
    if (is64) { s = ei[2 * e]; d = ei[2 * E + 2 * e]; }
    else      { s = ei[e];     d = ei[E + e]; }
    s32[e] = s;
    d32[e] = d;
    atomicAdd(&deg[d], 1);
}

// ---------------------------------------------------------------------------
// Hierarchical exclusive scan of (deg[i] + 1)  (self loop folded in here).
// 1024-elem chunks; single-wave top scan (NB <= 64 -> N <= 65536).
// ---------------------------------------------------------------------------
__global__ void k_scan1(const int* __restrict__ deg, int* __restrict__ offs,
                        int* __restrict__ bsum, int N) {
    __shared__ int wtot[4];
    __shared__ int wbase[4];
    int tid = threadIdx.x;
    int lane = tid & 63, wid = tid >> 6;
    int i0 = blockIdx.x * 1024 + tid * 4;
    int v[4];
    #pragma unroll
    for (int k = 0; k < 4; k++) v[k] = (i0 + k < N) ? deg[i0 + k] + 1 : 0;
    int t = v[0] + v[1] + v[2] + v[3];
    int incl = t;
    #pragma unroll
    for (int off = 1; off < 64; off <<= 1) {
        int u = __shfl_up(incl, off, 64);
        if (lane >= off) incl += u;
    }
    if (lane == 63) wtot[wid] = incl;
    __syncthreads();
    if (tid == 0) {
        int run = 0;
        #pragma unroll
        for (int w = 0; w < 4; w++) { wbase[w] = run; run += wtot[w]; }
        bsum[blockIdx.x] = run;
    }
    __syncthreads();
    int ebase = wbase[wid] + incl - t;
    #pragma unroll
    for (int k = 0; k < 4; k++) {
        if (i0 + k < N) offs[i0 + k] = ebase;
        ebase += v[k];
    }
}

__global__ void k_scan2(int* __restrict__ bsum, int* __restrict__ offs, int NB, int N) {
    int lane = threadIdx.x;           // 64 threads
    int v = (lane < NB) ? bsum[lane] : 0;
    int incl = v;
    #pragma unroll
    for (int off = 1; off < 64; off <<= 1) {
        int u = __shfl_up(incl, off, 64);
        if (lane >= off) incl += u;
    }
    if (lane < NB) bsum[lane] = incl - v;   // exclusive block base
    if (lane == 63) offs[N] = incl;         // grand total = E + N
}

__global__ void k_scan3(const int* __restrict__ bsum, int* __restrict__ offs,
                        int* __restrict__ cur, int N) {
    int add = bsum[blockIdx.x];
    int i0 = blockIdx.x * 1024 + threadIdx.x * 4;
    #pragma unroll
    for (int k = 0; k < 4; k++) {
        int i = i0 + k;
        if (i < N) { int o = offs[i] + add; offs[i] = o; cur[i] = o; }
    }
}

__global__ void k_fill(const int* __restrict__ s32, const int* __restrict__ d32,
                       int* __restrict__ cur, int* __restrict__ csr, int E, int N) {
    int i = blockIdx.x * 256 + threadIdx.x;
    if (i >= E + N) return;
    int s, d;
    if (i < E) { s = s32[i]; d = d32[i]; }
    else       { s = i - E;  d = i - E; }     // self loop
    int pos = atomicAdd(&cur[d], 1);
    csr[pos] = s;
}

// ---------------------------------------------------------------------------
// GEMM1 + fused att1: xw1h[N,128] (fp16) = x @ W1; asrc1/adst1 from fp32 acc.
// 16 rows / block of 256. Wave w: rows (w>>1)*8..+8, cols (w&1)*64..+64
// (= heads 2(w&1), 2(w&1)+1). 32-lane butterfly per row per head.
// ---------------------------------------------------------------------------
__global__ void k_gemm1(const float* __restrict__ x, const float* __restrict__ W,
                        const float* __restrict__ as1, const float* __restrict__ ad1,
                        __half* __restrict__ xwh, float* __restrict__ asrc,
                        float* __restrict__ adst, int N) {
    __shared__ float xs[16][128];
    int r0 = blockIdx.x * 16;
    for (int i = threadIdx.x; i < 16 * 32; i += 256) {   // 512 float4 = whole tile
        int q = i & 31;
        int r = i >> 5;
        int gr = r0 + r;
        float4 v = make_float4(0.f, 0.f, 0.f, 0.f);
        if (gr < N) v = ((const float4*)(x + (size_t)gr * 128))[q];
        ((float4*)xs)[i] = v;
    }
    __syncthreads();
    int c  = threadIdx.x & 127;
    int rg = threadIdx.x >> 7;
    int lane = threadIdx.x & 63;
    float acc[8] = {0.f, 0.f, 0.f, 0.f, 0.f, 0.f, 0.f, 0.f};
    #pragma unroll 8
    for (int k4 = 0; k4 < 32; k4++) {
        float w0 = W[(4 * k4 + 0) * 128 + c];
        float w1 = W[(4 * k4 + 1) * 128 + c];
        float w2 = W[(4 * k4 + 2) * 128 + c];
        float w3 = W[(4 * k4 + 3) * 128 + c];
        #pragma unroll
        for (int i = 0; i < 8; i++) {
            float4 xv = *(const float4*)&xs[rg * 8 + i][4 * k4];
            acc[i] += xv.x * w0 + xv.y * w1 + xv.z * w2 + xv.w * w3;
        }
    }
    float sa = as1[c], da = ad1[c];
    int h = c >> 5;                       // head owned by this 32-lane group
    #pragma unroll
    for (int i = 0; i < 8; i++) {
        int r = r0 + rg * 8 + i;
        if (r < N) xwh[(size_t)r * 128 + c] = __float2half(acc[i]);
        // attention dots: reduce acc[i]*att over the 32 lanes of this head
        float ps = acc[i] * sa;
        float pd = acc[i] * da;
        #pragma unroll
        for (int mk = 1; mk < 32; mk <<= 1) {
            ps += __shfl_xor(ps, mk);
            pd += __shfl_xor(pd, mk);
        }
        if ((lane & 31) == 0 && r < N) {
            asrc[r * 4 + h] = ps;
            adst[r * 4 + h] = pd;
        }
    }
}

// ---------------------------------------------------------------------------
// Layer-1 aggregation + fused GEMM2/att2 epilogue.
// One wave per dst node; lane -> head h = lane>>4, channels {ch, ch+1},
// ch = h*32 + 2*(lane&15). Online softmax, 4-edge unroll.
// Epilogue: h-row (relu'd) dotted with W2 (LDS, transposed) -> xw2[n][0..8],
// then asrc2/adst2. hbuf is never materialized.
// ---------------------------------------------------------------------------
__global__ void k_agg1(const __half* __restrict__ xwh, const float* __restrict__ asrc,
                       const float* __restrict__ adst, const int* __restrict__ offs,
                       const int* __restrict__ csr, const float* __restrict__ b1,
                       const float* __restrict__ W2, const float* __restrict__ as2,
                       const float* __restrict__ ad2, float* __restrict__ xw2,
                       float* __restrict__ asrc2, float* __restrict__ adst2, int N) {
    __shared__ float ws2t[8 * 128];       // W2 transposed: ws2t[c*128 + k]
    __shared__ float s_as2[8], s_ad2[8];
    for (int i = threadIdx.x; i < 1024; i += 256) {
        int k = i >> 3, cc = i & 7;       // W2[k][cc]
        ws2t[cc * 128 + k] = W2[i];
    }
    if (threadIdx.x < 8)  s_as2[threadIdx.x] = as2[threadIdx.x];
    else if (threadIdx.x < 16) s_ad2[threadIdx.x - 8] = ad2[threadIdx.x - 8];
    __syncthreads();

    int node = (blockIdx.x * blockDim.x + threadIdx.x) >> 6;
    int lane = threadIdx.x & 63;
    if (node >= N) return;
    int h  = lane >> 4;
    int ch = h * 32 + 2 * (lane & 15);
    float adst_h = adst[node * 4 + h];
    int beg = offs[node], end = offs[node + 1];
    float m = -3.0e38f, s = 0.f, a0 = 0.f, a1 = 0.f;
    int j = beg;
    for (; j + 4 <= end; j += 4) {
        int s0 = csr[j], s1 = csr[j + 1], s2 = csr[j + 2], s3 = csr[j + 3];
        float e0 = asrc[s0 * 4 + h] + adst_h;
        float e1 = asrc[s1 * 4 + h] + adst_h;
        float e2 = asrc[s2 * 4 + h] + adst_h;
        float e3 = asrc[s3 * 4 + h] + adst_h;
        float2 f0 = __half22float2(*(const __half2*)(xwh + (size_t)s0 * 128 + ch));
        float2 f1 = __half22float2(*(const __half2*)(xwh + (size_t)s1 * 128 + ch));
        float2 f2 = __half22float2(*(const __half2*)(xwh + (size_t)s2 * 128 + ch));
        float2 f3 = __half22float2(*(const __half2*)(xwh + (size_t)s3 * 128 + ch));
        e0 = (e0 > 0.f) ? e0 : SLOPE * e0;
        e1 = (e1 > 0.f) ? e1 : SLOPE * e1;
        e2 = (e2 > 0.f) ? e2 : SLOPE * e2;
        e3 = (e3 > 0.f) ? e3 : SLOPE * e3;
        float mn = fmaxf(fmaxf(m, fmaxf(e0, e1)), fmaxf(e2, e3));
        float sc = __expf(m - mn);
        float p0 = __expf(e0 - mn);
        float p1 = __expf(e1 - mn);
        float p2 = __expf(e2 - mn);
        float p3 = __expf(e3 - mn);
        s  = s  * sc + p0 + p1 + p2 + p3;
        a0 = a0 * sc + p0 * f0.x + p1 * f1.x + p2 * f2.x + p3 * f3.x;
        a1 = a1 * sc + p0 * f0.y + p1 * f1.y + p2 * f2.y + p3 * f3.y;
        m = mn;
    }
    for (; j < end; j++) {
        int s0 = csr[j];
        float e0 = asrc[s0 * 4 + h] + adst_h;
        float2 f0 = __half22float2(*(const __half2*)(xwh + (size_t)s0 * 128 + ch));
        e0 = (e0 > 0.f) ? e0 : SLOPE * e0;
        float mn = fmaxf(m, e0);
        float sc = __expf(m - mn);
        float p0 = __expf(e0 - mn);
        s  = s  * sc + p0;
        a0 = a0 * sc + p0 * f0.x;
        a1 = a1 * sc + p0 * f0.y;
        m = mn;
    }
    float inv = 1.f / s;
    float o0 = fmaxf(a0 * inv + b1[ch],     0.f);   // relu(h)
    float o1 = fmaxf(a1 * inv + b1[ch + 1], 0.f);

    // ---- fused GEMM2: xw2[node][c] = sum_ch h[ch]*W2[ch][c] ----
    float p[8];
    #pragma unroll
    for (int cc = 0; cc < 8; cc++)
        p[cc] = o0 * ws2t[cc * 128 + ch] + o1 * ws2t[cc * 128 + ch + 1];
    #pragma unroll
    for (int mk = 1; mk < 64; mk <<= 1) {
        #pragma unroll
        for (int cc = 0; cc < 8; cc++) p[cc] += __shfl_xor(p[cc], mk);
    }
    if (lane == 0) {
        float vs = 0.f, vd = 0.f;
        #pragma unroll
        for (int cc = 0; cc < 8; cc++) {
            xw2[node * 8 + cc] = p[cc];
            vs += p[cc] * s_as2[cc];
            vd += p[cc] * s_ad2[cc];
        }
        asrc2[node] = vs;
        adst2[node] = vd;
    }
}

// ---------------------------------------------------------------------------
// Layer-2 aggregation + log_softmax: 8 lanes per node, 4-edge unroll.
// ---------------------------------------------------------------------------
__global__ void k_agg2(const float* __restrict__ xw2, const float* __restrict__ asrc2,
                       const float* __restrict__ adst2, const int* __restrict__ offs,
                       const int* __restrict__ csr, const float* __restrict__ b2,
                       float* __restrict__ out, int N) {
    int gid  = blockIdx.x * blockDim.x + threadIdx.x;
    int lane = threadIdx.x & 63;
    int node = (gid >> 6) * 8 + (lane >> 3);
    int c    = lane & 7;
    if (node >= N) return;
    float adst = adst2[node];
    int beg = offs[node], end = offs[node + 1];
    float m = -3.0e38f, s = 0.f, acc = 0.f;
    int j = beg;
    for (; j + 4 <= end; j += 4) {
        int s0 = csr[j], s1 = csr[j + 1], s2 = csr[j + 2], s3 = csr[j + 3];
        float e0 = asrc2[s0] + adst;
        float e1 = asrc2[s1] + adst;
        float e2 = asrc2[s2] + adst;
        float e3 = asrc2[s3] + adst;
        float v0 = xw2[s0 * 8 + c];
        float v1 = xw2[s1 * 8 + c];
        float v2 = xw2[s2 * 8 + c];
        float v3 = xw2[s3 * 8 + c];
        e0 = (e0 > 0.f) ? e0 : SLOPE * e0;
        e1 = (e1 > 0.f) ? e1 : SLOPE * e1;
        e2 = (e2 > 0.f) ? e2 : SLOPE * e2;
        e3 = (e3 > 0.f) ? e3 : SLOPE * e3;
        float mn = fmaxf(fmaxf(m, fmaxf(e0, e1)), fmaxf(e2, e3));
        float sc = __expf(m - mn);
        float p0 = __expf(e0 - mn);
        float p1 = __expf(e1 - mn);
        float p2 = __expf(e2 - mn);
        float p3 = __expf(e3 - mn);
        s   = s   * sc + p0 + p1 + p2 + p3;
        acc = acc * sc + p0 * v0 + p1 * v1 + p2 * v2 + p3 * v3;
        m = mn;
    }
    for (; j < end; j++) {
        int s0 = csr[j];
        float e0 = asrc2[s0] + adst;
        float v0 = xw2[s0 * 8 + c];
        e0 = (e0 > 0.f) ? e0 : SLOPE * e0;
        float mn = fmaxf(m, e0);
        float sc = __expf(m - mn);
        float p0 = __expf(e0 - mn);
        s   = s   * sc + p0;
        acc = acc * sc + p0 * v0;
        m = mn;
    }
    float o = acc / s + b2[c];
    // log_softmax across 8 classes (8 contiguous lanes)
    float mx = o;
    mx = fmaxf(mx, __shfl_xor(mx, 1));
    mx = fmaxf(mx, __shfl_xor(mx, 2));
    mx = fmaxf(mx, __shfl_xor(mx, 4));
    float ex = __expf(o - mx);
    float se = ex;
    se += __shfl_xor(se, 1); se += __shfl_xor(se, 2); se += __shfl_xor(se, 4);
    out[node * 8 + c] = o - mx - __logf(se);
}

// ---------------------------------------------------------------------------
extern "C" void kernel_launch(void* const* d_in, const int* in_sizes, int n_in,
                              void* d_out, int out_size, void* d_ws, size_t ws_size,
                              hipStream_t stream) {
    const float* x   = (const float*)d_in[0];
    const int*   ei  = (const int*)d_in[1];
    const float* W1  = (const float*)d_in[2];
    const float* as1 = (const float*)d_in[3];
    const float* ad1 = (const float*)d_in[4];
    const float* b1  = (const float*)d_in[5];
    const float* W2  = (const float*)d_in[6];
    const float* as2 = (const float*)d_in[7];
    const float* ad2 = (const float*)d_in[8];
    const float* b2  = (const float*)d_in[9];
    float* out = (float*)d_out;

    int N = in_sizes[0] / F_IN;
    int E = in_sizes[1] / 2;
    int ET = E + N;                       // edges incl. self loops
    int NB = (N + 1023) / 1024;           // scan chunks (<=64 for N<=65536)

    // workspace carve (all regions fully written before read each call)
    char* p = (char*)d_ws;
    auto carve = [&](size_t bytes) { char* q = p; p += (bytes + 255) & ~(size_t)255; return (void*)q; };
    __half* xw1h = (__half*)carve((size_t)N * 128 * 2);
    float* asrc1 = (float*)carve((size_t)N * 4 * 4);
    float* adst1 = (float*)carve((size_t)N * 4 * 4);
    float* xw2   = (float*)carve((size_t)N * 8 * 4);
    float* asrc2 = (float*)carve((size_t)N * 4);
    float* adst2 = (float*)carve((size_t)N * 4);
    int*   deg   = (int*)carve((size_t)N * 4);
    int*   offs  = (int*)carve((size_t)(N + 1) * 4);
    int*   cur   = (int*)carve((size_t)N * 4);
    int*   bsum  = (int*)carve(64 * 4);
    int*   s32   = (int*)carve((size_t)E * 4);
    int*   d32   = (int*)carve((size_t)E * 4);
    int*   csr   = (int*)carve((size_t)ET * 4);

    // --- CSR build ---
    k_zero<<<(N + 255) / 256, 256, 0, stream>>>(deg, N);
    k_convert<<<(E + 255) / 256, 256, 0, stream>>>(ei, s32, d32, deg, E);
    k_scan1<<<NB, 256, 0, stream>>>(deg, offs, bsum, N);
    k_scan2<<<1, 64, 0, stream>>>(bsum, offs, NB, N);
    k_scan3<<<NB, 256, 0, stream>>>(bsum, offs, cur, N);
    k_fill<<<(ET + 255) / 256, 256, 0, stream>>>(s32, d32, cur, csr, E, N);

    // --- layer 1 (gemm1 + att1 fused) ---
    k_gemm1<<<(N + 15) / 16, 256, 0, stream>>>(x, W1, as1, ad1, xw1h, asrc1, adst1, N);

    // --- agg1 + gemm2 + att2 fused ---
    k_agg1<<<(N + 3) / 4, 256, 0, stream>>>(xw1h, asrc1, adst1, offs, csr, b1,
                                            W2, as2, ad2, xw2, asrc2, adst2, N);

    // --- layer 2 aggregation + log_softmax ---
    k_agg2<<<(N * 8 + 255) / 256, 256, 0, stream>>>(xw2, asrc2, adst2, offs, csr, b2, out, N);
}